// Round 6
// baseline (341.586 us; speedup 1.0000x reference)
//
#include <hip/hip_runtime.h>
#include <hip/hip_bf16.h>

#define D_DIM 768
#define HS 64
#define SEQ 4096
#define NBATCH 8

typedef short bf8 __attribute__((ext_vector_type(8)));   // 8 bf16 (4 VGPR) MFMA A/B frag
typedef short bf4 __attribute__((ext_vector_type(4)));   // 4 bf16 (8 B)
typedef float f4 __attribute__((ext_vector_type(4)));    // MFMA C/D frag

static __device__ __forceinline__ short f2b(float x) {
    __hip_bfloat16 h = __float2bfloat16(x);
    return __builtin_bit_cast(short, h);
}
// pack two fp32 -> bf16x2 dword (round-half-up): 2 add + 1 v_perm
static __device__ __forceinline__ unsigned pk2(float x, float y) {
    unsigned ux = __builtin_bit_cast(unsigned, x) + 0x8000u;
    unsigned uy = __builtin_bit_cast(unsigned, y) + 0x8000u;
    return __builtin_amdgcn_perm(uy, ux, 0x07060302u);  // {uy[3],uy[2],ux[3],ux[2]}
}

#if defined(__has_builtin)
#if __has_builtin(__builtin_amdgcn_exp2f)
#define EXP2F(x) __builtin_amdgcn_exp2f(x)
#endif
#endif
#ifndef EXP2F
#define EXP2F(x) exp2f(x)
#endif

// ---------------------------------------------------------------------------
// Kernel 0: W[768][64] fp32 x3 -> wt3 in MFMA-fragment-direct order:
//   wt3[(c32*192 + col)*32 + quad*8 + e] = W[k][n],  col = mat*64+n,
//   k = c32*32 + quad*8 + e. Softmax scale*log2(e) baked into Wq.
// ---------------------------------------------------------------------------
__global__ __launch_bounds__(256) void wconv_kernel(
    const float* __restrict__ Wk, const float* __restrict__ Wq,
    const float* __restrict__ Wv, short* __restrict__ wt3)
{
    int tid = blockIdx.x * 256 + threadIdx.x;
    int mat = tid / (D_DIM * HS);
    int rem = tid - mat * (D_DIM * HS);
    int k = rem >> 6;
    int n = rem & 63;
    const float* W = (mat == 0) ? Wk : (mat == 1) ? Wq : Wv;
    float scale = (mat == 1) ? 0.18033688011112042f : 1.0f;  // log2(e)/8
    int cc = mat * HS + n;
    int c = k >> 5, q = (k >> 3) & 3, e = k & 7;
    wt3[(c * 192 + cc) * 32 + q * 8 + e] = f2b(W[rem] * scale);
}

// ---------------------------------------------------------------------------
// Kernel 1: projections. [32768 x 768] @ [768 x 192] -> q,k,v bf16 [B*S][64].
// 1024 blocks x 256 thr; block = 32-row M-tile, wave = 48 cols.
// R6: manual unroll-by-2 with NAMED register dbuf (wbA/wbB) — R5's full-unroll
// pragma + wb[p] risked hoist-all/dynamic-index spill. (256,4): est ~116 VGPR.
// ---------------------------------------------------------------------------
__global__ __launch_bounds__(256, 4) void proj_kernel(
    const float* __restrict__ ix, const short* __restrict__ wt3,
    short* __restrict__ qg, short* __restrict__ kg, short* __restrict__ vg)
{
    __shared__ short ixl[2][32 * 72];   // [row][k 0..64), stride 72

    const int t = threadIdx.x;
    const int wave = t >> 6, lane = t & 63;
    const int m = lane & 15, quad = lane >> 4;
    const int m0 = blockIdx.x * 32;

    const int srow = t >> 3;          // ix staging: row 0..31
    const int skoff = (t & 7) * 8;    // float col 0,8,..,56

    f4 xr0, xr1;
    auto load_ix = [&](int c) {
        const float* px = ix + (m0 + srow) * D_DIM + c * 64 + skoff;
        xr0 = *(const f4*)px;
        xr1 = *(const f4*)(px + 4);
    };
    auto write_ix = [&](int p) {
        bf8 xw;
        #pragma unroll
        for (int i = 0; i < 4; ++i) { xw[i] = f2b(xr0[i]); xw[i + 4] = f2b(xr1[i]); }
        *(bf8*)(&ixl[p][srow * 72 + skoff]) = xw;
    };

    const int colb = wave * 48;
    const short* wbase = wt3 + (colb + m) * 32 + quad * 8;

    bf8 wbA[2][3], wbB[2][3];   // [k-half][nt] — two named register buffers
    auto load_w = [&](int c, bf8 (&dst)[2][3]) {
        #pragma unroll
        for (int nt = 0; nt < 3; ++nt) {
            const short* pw = wbase + ((size_t)(2 * c) * 192 + nt * 16) * 32;
            dst[0][nt] = *(const bf8*)pw;
            dst[1][nt] = *(const bf8*)(pw + 192 * 32);
        }
    };

    f4 acc[2][3] = {};

    auto compute = [&](const bf8 (&wb)[2][3], int p) {
        bf8 a0 = *(const bf8*)(&ixl[p][m * 72 + quad * 8]);
        bf8 a1 = *(const bf8*)(&ixl[p][m * 72 + 32 + quad * 8]);
        bf8 a2 = *(const bf8*)(&ixl[p][(16 + m) * 72 + quad * 8]);
        bf8 a3 = *(const bf8*)(&ixl[p][(16 + m) * 72 + 32 + quad * 8]);
        #pragma unroll
        for (int nt = 0; nt < 3; ++nt) {
            acc[0][nt] = __builtin_amdgcn_mfma_f32_16x16x32_bf16(a0, wb[0][nt], acc[0][nt], 0, 0, 0);
            acc[0][nt] = __builtin_amdgcn_mfma_f32_16x16x32_bf16(a1, wb[1][nt], acc[0][nt], 0, 0, 0);
            acc[1][nt] = __builtin_amdgcn_mfma_f32_16x16x32_bf16(a2, wb[0][nt], acc[1][nt], 0, 0, 0);
            acc[1][nt] = __builtin_amdgcn_mfma_f32_16x16x32_bf16(a3, wb[1][nt], acc[1][nt], 0, 0, 0);
        }
    };

    load_ix(0); load_w(0, wbA); write_ix(0); __syncthreads();

    for (int cc = 0; cc < 6; ++cc) {    // 12 chunks, unroll-by-2
        const int c0 = 2 * cc, c1 = c0 + 1;
        // iter A: compute c0 (ixl[0], wbA), prefetch c1 -> (regs, wbB)
        load_ix(c1); load_w(c1, wbB);
        compute(wbA, 0);
        write_ix(1); __syncthreads();
        // iter B: compute c1 (ixl[1], wbB), prefetch c0+2 -> (regs, wbA)
        if (cc < 5) { load_ix(c0 + 2); load_w(c0 + 2, wbA); }
        compute(wbB, 1);
        if (cc < 5) { write_ix(0); __syncthreads(); }
    }

    // epilogue: C/D frag row = quad*4+r (ix row), col = lane&15 (wt col)
    #pragma unroll
    for (int mt = 0; mt < 2; ++mt) {
        const int row = m0 + mt * 16 + quad * 4;
        #pragma unroll
        for (int nt = 0; nt < 3; ++nt) {
            const int cb = colb + nt * 16;
            short* op = (cb < 64) ? kg : (cb < 128) ? qg : vg;  // d_in order: Wk,Wq,Wv
            const int n = (cb & 63) + m;
            #pragma unroll
            for (int r = 0; r < 4; ++r)
                op[(row + r) * HS + n] = f2b(acc[mt][nt][r]);
        }
    }
}

// ---------------------------------------------------------------------------
// Kernel 2: fused attention, 4-way key split, 512 blocks x 256 thr,
// 64 queries/wave (nq=4). R6 restructure:
//  - K fragments come DIRECT FROM GLOBAL (L2-resident, XCD-pinned), register
//    double-buffered one chunk ahead (kfA/kfB) — kl LDS buffer deleted.
//    Halves per-wave LDS reads (16->8 b128/chunk) and kills K staging writes;
//    per-CU LDS pipe (~8 us) now sits below the MFMA floor (~16.6 us).
//  - V staging: thread owns 4 consecutive j x 4 d -> 8 b64 LDS writes
//    (was 16 b32). Read-side layout contract unchanged from R5:
//    element (d, j=32g+16h+4q+r) at chunk (4g+q)^((d&7)^(d>>3)), col h*4+r.
//  - Manual unroll-by-2 so all register-buffer indices are literals.
// pf trick unchanged: concat of two 16-row S^T C-frags post exp+pack is
// per-lane a valid 16x16x32 B-frag under row-perm pi baked into vl's layout.
// ---------------------------------------------------------------------------
__global__ __launch_bounds__(256, 2) void attn_kernel(
    const short* __restrict__ qg, const short* __restrict__ kg,
    const short* __restrict__ vg, float* __restrict__ num0,
    float* __restrict__ num1, float* __restrict__ num2,
    float* __restrict__ num3, float* __restrict__ den0,
    float* __restrict__ den1, float* __restrict__ den2,
    float* __restrict__ den3)
{
    __shared__ short vl[2][64 * 64];

    const int t = threadIdx.x;
    const int wave = t >> 6, lane = t & 63;
    const int m = lane & 15, quad = lane >> 4;

    // XCD-aware remap: batch = XCD index (512 blocks, 64 per XCD)
    const int flat = blockIdx.x;
    const int lg = (flat & 7) * 64 + (flat >> 3);
    const int qx = lg & 15;
    const int ks = (lg >> 4) & 3;
    const int b  = lg >> 6;

    const int rbase = b * SEQ;
    const int kbase = rbase + ks * (SEQ / 4);
    const int qw = qx * 256 + wave * 64;

    float* __restrict__ nump = (ks == 0) ? num0 : (ks == 1) ? num1 : (ks == 2) ? num2 : num3;
    float* __restrict__ denp = (ks == 0) ? den0 : (ks == 1) ? den1 : (ks == 2) ? den2 : den3;

    // persistent Q B-frags: lane n=q=lane&15, k=d=quad*8+e (+32 per step)
    bf8 qf[4][2];
    #pragma unroll
    for (int nq = 0; nq < 4; ++nq)
        #pragma unroll
        for (int st = 0; st < 2; ++st)
            qf[nq][st] = *(const bf8*)(qg + (rbase + qw + nq * 16 + m) * HS + st * 32 + quad * 8);

    // V staging: thread = (jq 0..15, dq 0..15): rows 4jq..4jq+3, d 4dq..4dq+3
    const int jq = t >> 4, dq = t & 15;
    const int vgj = jq >> 3, vh = (jq >> 2) & 1, vq = jq & 3;
    const int vchunk_l = 4 * vgj + vq;
    const int vcol = vh * 4;

    ushort4 vr[4];
    auto load_v = [&](int c) {
        const short* pv = vg + (size_t)(kbase + c * 64 + jq * 4) * HS + dq * 4;
        #pragma unroll
        for (int r = 0; r < 4; ++r) vr[r] = *(const ushort4*)(pv + r * HS);
    };
    auto write_v = [&](int p) {
        #pragma unroll
        for (int i = 0; i < 4; ++i) {
            const int d = dq * 4 + i;
            const int chunk = vchunk_l ^ ((d & 7) ^ (d >> 3));
            unsigned short e0 = (i == 0) ? vr[0].x : (i == 1) ? vr[0].y : (i == 2) ? vr[0].z : vr[0].w;
            unsigned short e1 = (i == 0) ? vr[1].x : (i == 1) ? vr[1].y : (i == 2) ? vr[1].z : vr[1].w;
            unsigned short e2 = (i == 0) ? vr[2].x : (i == 1) ? vr[2].y : (i == 2) ? vr[2].z : vr[2].w;
            unsigned short e3 = (i == 0) ? vr[3].x : (i == 1) ? vr[3].y : (i == 2) ? vr[3].z : vr[3].w;
            ushort4 w; w.x = e0; w.y = e1; w.z = e2; w.w = e3;   // cols r=0..3
            *(ushort4*)(&vl[p][d * 64 + chunk * 8 + vcol]) = w;
        }
    };

    // K fragment register dbuf: [g][{A0,A1,B0,B1}] per buffer
    bf8 kfA[2][4], kfB[2][4];
    auto load_k = [&](int c, bf8 (&dst)[2][4]) {
        #pragma unroll
        for (int g = 0; g < 2; ++g) {
            const short* pk = kg + (size_t)(kbase + c * 64 + g * 32 + m) * HS + quad * 8;
            dst[g][0] = *(const bf8*)pk;
            dst[g][1] = *(const bf8*)(pk + 32);
            dst[g][2] = *(const bf8*)(pk + 16 * HS);
            dst[g][3] = *(const bf8*)(pk + 16 * HS + 32);
        }
    };

    f4 o[4][4] = {};
    float den[4] = {0.f, 0.f, 0.f, 0.f};

    auto compute = [&](const bf8 (&kc)[2][4], int p) {
        #pragma unroll
        for (int g = 0; g < 2; ++g) {
            bf8 vf[4];
            #pragma unroll
            for (int dt = 0; dt < 4; ++dt) {
                const int row = dt * 16 + m;
                const int key = (m & 7) ^ (2 * dt + (m >> 3));
                const int chunk = (g * 4 + quad) ^ key;
                vf[dt] = *(const bf8*)(&vl[p][row * 64 + chunk * 8]);
            }
            #pragma unroll
            for (int nq = 0; nq < 4; ++nq) {
                f4 sa = {0.f, 0.f, 0.f, 0.f}, sb = {0.f, 0.f, 0.f, 0.f};
                sa = __builtin_amdgcn_mfma_f32_16x16x32_bf16(kc[g][0], qf[nq][0], sa, 0, 0, 0);
                sa = __builtin_amdgcn_mfma_f32_16x16x32_bf16(kc[g][1], qf[nq][1], sa, 0, 0, 0);
                sb = __builtin_amdgcn_mfma_f32_16x16x32_bf16(kc[g][2], qf[nq][0], sb, 0, 0, 0);
                sb = __builtin_amdgcn_mfma_f32_16x16x32_bf16(kc[g][3], qf[nq][1], sb, 0, 0, 0);
                float e0 = EXP2F(sa[0]), e1 = EXP2F(sa[1]), e2 = EXP2F(sa[2]), e3 = EXP2F(sa[3]);
                float e4 = EXP2F(sb[0]), e5 = EXP2F(sb[1]), e6 = EXP2F(sb[2]), e7 = EXP2F(sb[3]);
                den[nq] += ((e0 + e1) + (e2 + e3)) + ((e4 + e5) + (e6 + e7));
                uint4 pu;
                pu.x = pk2(e0, e1); pu.y = pk2(e2, e3);
                pu.z = pk2(e4, e5); pu.w = pk2(e6, e7);
                bf8 pf = __builtin_bit_cast(bf8, pu);
                #pragma unroll
                for (int dt = 0; dt < 4; ++dt)
                    o[nq][dt] = __builtin_amdgcn_mfma_f32_16x16x32_bf16(vf[dt], pf, o[nq][dt], 0, 0, 0);
            }
        }
    };

    load_v(0); load_k(0, kfA); write_v(0); __syncthreads();

    const int NCH = SEQ / 4 / 64;   // 16 chunks of 64 keys
    for (int cc = 0; cc < NCH / 2; ++cc) {
        const int c0 = 2 * cc, c1 = c0 + 1;
        // iter A: compute c0 (vl[0], kfA); prefetch c1 -> (vr, kfB)
        load_v(c1); load_k(c1, kfB);
        compute(kfA, 0);
        write_v(1); __syncthreads();
        // iter B: compute c1 (vl[1], kfB); prefetch c0+2 -> (vr, kfA)
        if (cc < NCH / 2 - 1) { load_v(c0 + 2); load_k(c0 + 2, kfA); }
        compute(kfB, 1);
        if (cc < NCH / 2 - 1) { write_v(0); __syncthreads(); }
    }

    // epilogue: O^T frag row=d=dt*16+quad*4+r, col=q=lane&15. Partial sums out.
    #pragma unroll
    for (int nq = 0; nq < 4; ++nq) {
        float d = den[nq];
        d += __shfl_xor(d, 16, 64);
        d += __shfl_xor(d, 32, 64);
        const int orow = rbase + qw + nq * 16 + m;
        if (quad == 0) denp[orow] = d;
        #pragma unroll
        for (int dt = 0; dt < 4; ++dt)
            *(f4*)(nump + orow * HS + dt * 16 + quad * 4) = o[nq][dt];
    }
}

// ---------------------------------------------------------------------------
// Kernel 3: combine the four key-splits: out = sum(num_i)/sum(den_i).
// ---------------------------------------------------------------------------
__global__ __launch_bounds__(256) void reduce_kernel(
    float* __restrict__ out, const float* __restrict__ num1,
    const float* __restrict__ num2, const float* __restrict__ num3,
    const float* __restrict__ den0, const float* __restrict__ den1,
    const float* __restrict__ den2, const float* __restrict__ den3)
{
    const int gid = blockIdx.x * 256 + threadIdx.x;
    const int base = gid * 4;
    const int r = base >> 6;
    f4 n0 = *(const f4*)(out + base);
    f4 n1 = *(const f4*)(num1 + base);
    f4 n2 = *(const f4*)(num2 + base);
    f4 n3 = *(const f4*)(num3 + base);
    const float rs = 1.0f / ((den0[r] + den1[r]) + (den2[r] + den3[r]));
    f4 res;
    #pragma unroll
    for (int i = 0; i < 4; ++i) res[i] = ((n0[i] + n1[i]) + (n2[i] + n3[i])) * rs;
    *(f4*)(out + base) = res;
}

extern "C" void kernel_launch(void* const* d_in, const int* in_sizes, int n_in,
                              void* d_out, int out_size, void* d_ws, size_t ws_size,
                              hipStream_t stream) {
    const float* ix = (const float*)d_in[0];
    const float* Wk = (const float*)d_in[1];
    const float* Wq = (const float*)d_in[2];
    const float* Wv = (const float*)d_in[3];
    float* out = (float*)d_out;

    const size_t NQKV = (size_t)NBATCH * SEQ * HS;      // 2,097,152 elements
    short* qg = (short*)d_ws;
    short* kg = qg + NQKV;
    short* vg = kg + NQKV;
    short* wt3 = vg + NQKV;                             // 24*192*32 = 147456 shorts
    char*  fbase = (char*)(wt3 + 24 * 192 * 32);        // 16B-aligned
    float* num1 = (float*)fbase;
    float* num2 = num1 + NQKV;
    float* num3 = num2 + NQKV;
    float* den0 = num3 + NQKV;
    float* den1 = den0 + (size_t)NBATCH * SEQ;
    float* den2 = den1 + (size_t)NBATCH * SEQ;
    float* den3 = den2 + (size_t)NBATCH * SEQ;

    wconv_kernel<<<(3 * D_DIM * HS) / 256, 256, 0, stream>>>(Wk, Wq, Wv, wt3);
    proj_kernel<<<(NBATCH * SEQ) / 32, 256, 0, stream>>>(ix, wt3, qg, kg, vg);
    attn_kernel<<<512, 256, 0, stream>>>(qg, kg, vg, out, num1, num2, num3,
                                         den0, den1, den2, den3);
    reduce_kernel<<<(int)(NQKV / (256 * 4)), 256, 0, stream>>>(
        out, num1, num2, num3, den0, den1, den2, den3);
}